// Round 1
// baseline (6562.213 us; speedup 1.0000x reference)
//
#include <hip/hip_runtime.h>
#include <stdint.h>

#define VOCAB 32000
#define EMBD  256
#define HID   512
#define SEQ   32
#define NB    32

using bf16x8 = __attribute__((ext_vector_type(8))) short;
using f32x4  = __attribute__((ext_vector_type(4))) float;

__device__ __forceinline__ unsigned short f2bf(float x){
    unsigned int u = __float_as_uint(x);
    u += 0x7fffu + ((u >> 16) & 1u);
    return (unsigned short)(u >> 16);
}
__device__ __forceinline__ float sigm(float x){ return 1.0f / (1.0f + expf(-x)); }

// ---------------- prep: Wh -> bf16, h0 = enc_last, c0 = 0 ----------------
__global__ __launch_bounds__(256) void prep_kernel(
    const float* __restrict__ Wh, unsigned short* __restrict__ Whbf,
    const float* __restrict__ encl, float* __restrict__ h0, float* __restrict__ c0)
{
    int gid = blockIdx.x * 256 + threadIdx.x;
    if (gid < NB * HID) { h0[gid] = encl[gid]; c0[gid] = 0.f; }
    int stride = gridDim.x * 256;
    const int n4 = (VOCAB * HID) / 4;
    for (int i = gid; i < n4; i += stride) {
        float4 v = ((const float4*)Wh)[i];
        ushort4 r;
        r.x = f2bf(v.x); r.y = f2bf(v.y); r.z = f2bf(v.z); r.w = f2bf(v.w);
        ((ushort4*)Whbf)[i] = r;
    }
}

// ---------------- key_proj = enc @ Ua^T + Ua_b ----------------
__global__ __launch_bounds__(256) void keyproj_kernel(
    const float* __restrict__ enc, const float* __restrict__ Ua,
    const float* __restrict__ Uab, float* __restrict__ kp)
{
    __shared__ float es[8][HID];
    int b  = blockIdx.x >> 2;
    int l0 = (blockIdx.x & 3) * 8;
    for (int idx = threadIdx.x; idx < 8 * HID; idx += 256) {
        int l = idx >> 9, k = idx & 511;
        es[l][k] = enc[(b * SEQ + l0 + l) * HID + k];
    }
    __syncthreads();
    for (int jj = 0; jj < 2; ++jj) {
        int j = threadIdx.x + jj * 256;
        const float4* ua = (const float4*)(Ua + j * HID);
        float acc[8] = {0.f,0.f,0.f,0.f,0.f,0.f,0.f,0.f};
        for (int k4 = 0; k4 < HID / 4; ++k4) {
            float4 w = ua[k4];
            #pragma unroll
            for (int l = 0; l < 8; ++l) {
                float4 e = *(const float4*)&es[l][k4 * 4];
                acc[l] += w.x * e.x + w.y * e.y + w.z * e.z + w.w * e.w;
            }
        }
        float bias = Uab[j];
        #pragma unroll
        for (int l = 0; l < 8; ++l)
            kp[(b * SEQ + l0 + l) * HID + j] = acc[l] + bias;
    }
}

// ---------------- per-step kernel: gates(t) | Wc(t-2) | attention(t-1) ----------------
__global__ __launch_bounds__(256) void step_kernel(
    int t,
    const int* __restrict__ tgt, const int* __restrict__ sosp,
    const int* __restrict__ mask,
    const float* __restrict__ enc, const float* __restrict__ emb,
    const float* __restrict__ W_ih, const float* __restrict__ W_hh,
    const float* __restrict__ b_ih, const float* __restrict__ b_hh,
    const float* __restrict__ Wa, const float* __restrict__ Wab,
    const float* __restrict__ va, const float* __restrict__ vab,
    const float* __restrict__ Wc, const float* __restrict__ Wcb,
    const float* __restrict__ kp,
    float* __restrict__ h_hist,   // [33][NB][HID]
    float* __restrict__ c_ws,     // [NB][HID]
    float* __restrict__ ctx_ws,   // [SEQ][NB][HID]
    unsigned short* __restrict__ A_bf) // [NB*SEQ][HID] bf16
{
    __shared__ float sm[10240];
    const int blk = blockIdx.x;
    const int tid = threadIdx.x;

    if (blk < 64) {
        // ---- GATES for step t: h_hist[t] -> h_hist[t+1], c ----
        if (t > 31) return;
        const int b = tid & 31, jl = tid >> 5;
        const int j = blk * 8 + jl;
        float acc0 = b_ih[j]        + b_hh[j];
        float acc1 = b_ih[512 + j]  + b_hh[512 + j];
        float acc2 = b_ih[1024 + j] + b_hh[1024 + j];
        float acc3 = b_ih[1536 + j] + b_hh[1536 + j];

        // phase X: x_t @ W_ih^T  (x_t = emb[token])
        const int sos = sosp[0];
        for (int idx = tid; idx < 32 * EMBD; idx += 256) {
            int bb = idx >> 8, k = idx & 255;
            int tok = (t == 0) ? sos : tgt[bb * SEQ + (t - 1)];
            sm[bb * 261 + k] = emb[tok * EMBD + k];
        }
        __syncthreads();
        {
            const float* w0 = W_ih + j * EMBD;
            const float* w1 = W_ih + (512 + j) * EMBD;
            const float* w2 = W_ih + (1024 + j) * EMBD;
            const float* w3 = W_ih + (1536 + j) * EMBD;
            const float* xs = sm + b * 261;
            for (int k4 = 0; k4 < EMBD / 4; ++k4) {
                float4 a = *(const float4*)(w0 + k4 * 4);
                float4 f = *(const float4*)(w1 + k4 * 4);
                float4 g = *(const float4*)(w2 + k4 * 4);
                float4 o = *(const float4*)(w3 + k4 * 4);
                float x0 = xs[k4*4], x1 = xs[k4*4+1], x2 = xs[k4*4+2], x3 = xs[k4*4+3];
                acc0 += a.x*x0 + a.y*x1 + a.z*x2 + a.w*x3;
                acc1 += f.x*x0 + f.y*x1 + f.z*x2 + f.w*x3;
                acc2 += g.x*x0 + g.y*x1 + g.z*x2 + g.w*x3;
                acc3 += o.x*x0 + o.y*x1 + o.z*x2 + o.w*x3;
            }
        }
        __syncthreads();

        // phases H0/H1: h @ W_hh^T in two 256-wide k chunks
        const float* hsrc = h_hist + t * (NB * HID);
        for (int ph = 0; ph < 2; ++ph) {
            for (int idx = tid; idx < 32 * 256; idx += 256) {
                int bb = idx >> 8, k = idx & 255;
                sm[bb * 261 + k] = hsrc[bb * 512 + ph * 256 + k];
            }
            __syncthreads();
            const float* w0 = W_hh + j * HID + ph * 256;
            const float* w1 = W_hh + (512 + j) * HID + ph * 256;
            const float* w2 = W_hh + (1024 + j) * HID + ph * 256;
            const float* w3 = W_hh + (1536 + j) * HID + ph * 256;
            const float* hs = sm + b * 261;
            for (int k4 = 0; k4 < 64; ++k4) {
                float4 a = *(const float4*)(w0 + k4 * 4);
                float4 f = *(const float4*)(w1 + k4 * 4);
                float4 g = *(const float4*)(w2 + k4 * 4);
                float4 o = *(const float4*)(w3 + k4 * 4);
                float x0 = hs[k4*4], x1 = hs[k4*4+1], x2 = hs[k4*4+2], x3 = hs[k4*4+3];
                acc0 += a.x*x0 + a.y*x1 + a.z*x2 + a.w*x3;
                acc1 += f.x*x0 + f.y*x1 + f.z*x2 + f.w*x3;
                acc2 += g.x*x0 + g.y*x1 + g.z*x2 + g.w*x3;
                acc3 += o.x*x0 + o.y*x1 + o.z*x2 + o.w*x3;
            }
            __syncthreads();
        }
        // LSTM cell
        float ig = sigm(acc0), fg = sigm(acc1);
        float gg = tanhf(acc2), og = sigm(acc3);
        float c_old = c_ws[b * HID + j];
        float c_new = fg * c_old + ig * gg;
        float h_new = og * tanhf(c_new);
        c_ws[b * HID + j] = c_new;
        h_hist[(t + 1) * (NB * HID) + b * HID + j] = h_new;

    } else if (blk < 128) {
        // ---- WC for step s = t-2: a = tanh([ctx,h] @ Wc^T + Wcb) -> A_bf ----
        if (t < 2 || t > 33) return;
        const int s = t - 2;
        const int b = tid & 31, jl = tid >> 5;
        const int j = (blk - 64) * 8 + jl;
        float acc = Wcb[j];
        const float* ctxs = ctx_ws + s * (NB * HID);
        const float* hs   = h_hist + (s + 1) * (NB * HID);
        for (int ph = 0; ph < 4; ++ph) {
            const float* src = (ph < 2) ? (ctxs + (ph & 1) * 256) : (hs + (ph & 1) * 256);
            for (int idx = tid; idx < 32 * 256; idx += 256) {
                int bb = idx >> 8, k = idx & 255;
                sm[bb * 261 + k] = src[bb * 512 + k];
            }
            __syncthreads();
            const float* w = Wc + j * 1024 + ph * 256;
            const float* cs = sm + b * 261;
            for (int k4 = 0; k4 < 64; ++k4) {
                float4 wv = *(const float4*)(w + k4 * 4);
                acc += wv.x*cs[k4*4] + wv.y*cs[k4*4+1] + wv.z*cs[k4*4+2] + wv.w*cs[k4*4+3];
            }
            __syncthreads();
        }
        A_bf[(b * SEQ + s) * HID + j] = f2bf(tanhf(acc));

    } else {
        // ---- ATTENTION for step s = t-1 (one block per batch b) ----
        if (t < 1 || t > 32) return;
        const int s = t - 1;
        const int b = blk - 128;
        const float* hs = h_hist + (s + 1) * (NB * HID) + b * HID;
        float* qs  = sm;            // 512
        float* hsh = sm + 512;      // 512
        float* vas = sm + 1024;     // 512
        float* kps = sm + 1536;     // 32*264 = 8448
        float* ss  = sm + 9984;     // 32
        float* es  = sm + 10016;    // 32
        for (int k = tid; k < HID; k += 256) { hsh[k] = hs[k]; vas[k] = va[k]; }
        __syncthreads();
        // q = h @ Wa^T + Wab
        for (int jj = 0; jj < 2; ++jj) {
            int j = tid + jj * 256;
            const float4* wa = (const float4*)(Wa + j * HID);
            float q = Wab[j];
            for (int k4 = 0; k4 < HID / 4; ++k4) {
                float4 w = wa[k4];
                q += w.x*hsh[k4*4] + w.y*hsh[k4*4+1] + w.z*hsh[k4*4+2] + w.w*hsh[k4*4+3];
            }
            qs[j] = q;
        }
        __syncthreads();
        // scores: s[l] = sum_j va[j]*tanh(q[j] + kp[b][l][j])
        const int l = tid >> 3, jt = tid & 7;
        float sp = 0.f;
        const float* kpb = kp + (b * SEQ) * HID;
        for (int ph = 0; ph < 2; ++ph) {
            for (int idx = tid; idx < 32 * 256; idx += 256) {
                int ll = idx >> 8, k = idx & 255;
                kps[ll * 264 + k] = kpb[ll * 512 + ph * 256 + k];
            }
            __syncthreads();
            for (int jj = 0; jj < 32; ++jj) {
                int jp = jt + (jj << 3);
                int j  = ph * 256 + jp;
                sp += vas[j] * tanhf(qs[j] + kps[l * 264 + jp]);
            }
            __syncthreads();
        }
        sp += __shfl_xor(sp, 1);
        sp += __shfl_xor(sp, 2);
        sp += __shfl_xor(sp, 4);
        if (jt == 0) {
            float sc = sp + vab[0];
            if (mask[b * SEQ + l] == 0) sc = -1e10f;
            ss[l] = sc;
        }
        __syncthreads();
        float m = -3e38f;
        for (int i = 0; i < 32; ++i) m = fmaxf(m, ss[i]);
        if (tid < 32) es[tid] = expf(ss[tid] - m);
        __syncthreads();
        float sum = 0.f;
        for (int i = 0; i < 32; ++i) sum += es[i];
        float rsum = 1.0f / sum;
        const float* encb = enc + (b * SEQ) * HID;
        for (int jj = 0; jj < 2; ++jj) {
            int j = tid + jj * 256;
            float cacc = 0.f;
            for (int ll = 0; ll < 32; ++ll)
                cacc += es[ll] * encb[ll * HID + j];
            ctx_ws[s * (NB * HID) + b * HID + j] = cacc * rsum;
        }
    }
}

// ---------------- final GEMM: out[1024][32000] = A[1024][512] @ Wh^T + bias ----------------
__global__ __launch_bounds__(256) void gemm_out(
    const unsigned short* __restrict__ A, const unsigned short* __restrict__ W,
    const float* __restrict__ bias, float* __restrict__ out)
{
    __shared__ unsigned short At[128 * 32];
    __shared__ unsigned short Bt[128 * 32];
    const int nb = blockIdx.x;          // 0..249
    const int mb = blockIdx.y;          // 0..7
    const int M0 = mb * 128, N0 = nb * 128;
    const int tid  = threadIdx.x;
    const int lane = tid & 63, wv = tid >> 6;
    const int wr = wv >> 1, wc = wv & 1;

    f32x4 acc[4][4];
    #pragma unroll
    for (int i = 0; i < 4; ++i)
        #pragma unroll
        for (int j = 0; j < 4; ++j)
            acc[i][j] = (f32x4){0.f, 0.f, 0.f, 0.f};

    for (int kt = 0; kt < 16; ++kt) {
        const int k0 = kt * 32;
        __syncthreads();
        for (int c = tid; c < 512; c += 256) {
            int row = c >> 2, cq = c & 3;
            *(uint4*)&At[row * 32 + cq * 8] = *(const uint4*)&A[(M0 + row) * 512 + k0 + cq * 8];
        }
        for (int c = tid; c < 512; c += 256) {
            int row = c >> 2, cq = c & 3;
            *(uint4*)&Bt[row * 32 + cq * 8] = *(const uint4*)&W[(N0 + row) * 512 + k0 + cq * 8];
        }
        __syncthreads();
        bf16x8 fa[4], fb[4];
        const int koff = (lane >> 4) * 8;
        #pragma unroll
        for (int i = 0; i < 4; ++i) {
            fa[i] = *(const bf16x8*)&At[(wr * 64 + i * 16 + (lane & 15)) * 32 + koff];
            fb[i] = *(const bf16x8*)&Bt[(wc * 64 + i * 16 + (lane & 15)) * 32 + koff];
        }
        #pragma unroll
        for (int i = 0; i < 4; ++i)
            #pragma unroll
            for (int j = 0; j < 4; ++j)
                acc[i][j] = __builtin_amdgcn_mfma_f32_16x16x32_bf16(fa[i], fb[j], acc[i][j], 0, 0, 0);
    }
    const int rbase = (lane >> 4) * 4;
    const int cbase = lane & 15;
    #pragma unroll
    for (int i = 0; i < 4; ++i) {
        #pragma unroll
        for (int j = 0; j < 4; ++j) {
            int col = N0 + wc * 64 + j * 16 + cbase;
            float bv = bias[col];
            #pragma unroll
            for (int r = 0; r < 4; ++r) {
                int row = M0 + wr * 64 + i * 16 + rbase + r;
                out[row * VOCAB + col] = acc[i][j][r] + bv;
            }
        }
    }
}

extern "C" void kernel_launch(void* const* d_in, const int* in_sizes, int n_in,
                              void* d_out, int out_size, void* d_ws, size_t ws_size,
                              hipStream_t stream)
{
    const int*   mask = (const int*)d_in[0];
    const float* enc  = (const float*)d_in[1];
    const float* encl = (const float*)d_in[2];
    const int*   tgt  = (const int*)d_in[3];
    const int*   sosp = (const int*)d_in[4];
    const float* emb  = (const float*)d_in[5];
    const float* W_ih = (const float*)d_in[6];
    const float* W_hh = (const float*)d_in[7];
    const float* b_ih = (const float*)d_in[8];
    const float* b_hh = (const float*)d_in[9];
    const float* Wa   = (const float*)d_in[10];
    const float* Wab  = (const float*)d_in[11];
    const float* Ua   = (const float*)d_in[12];
    const float* Uab  = (const float*)d_in[13];
    const float* va   = (const float*)d_in[14];
    const float* vab  = (const float*)d_in[15];
    const float* Wc   = (const float*)d_in[16];
    const float* Wcb  = (const float*)d_in[17];
    const float* Wh   = (const float*)d_in[18];
    const float* Whb  = (const float*)d_in[19];

    char* ws = (char*)d_ws;
    float* h_hist = (float*)(ws);                       // 33*32*512 f32 = 2,162,688 B
    float* c_ws   = (float*)(ws + 2162688);             // 65,536 B
    float* ctx_ws = (float*)(ws + 2228224);             // 2,097,152 B
    float* kp     = (float*)(ws + 4325376);             // 2,097,152 B
    unsigned short* A_bf  = (unsigned short*)(ws + 6422528);  // 1,048,576 B
    unsigned short* Wh_bf = (unsigned short*)(ws + 7471104);  // 32,768,000 B  (total ~40.2 MB)

    prep_kernel<<<2048, 256, 0, stream>>>(Wh, Wh_bf, encl, h_hist, c_ws);
    keyproj_kernel<<<128, 256, 0, stream>>>(enc, Ua, Uab, kp);
    for (int t = 0; t <= 33; ++t)
        step_kernel<<<160, 256, 0, stream>>>(t, tgt, sosp, mask, enc, emb,
            W_ih, W_hh, b_ih, b_hh, Wa, Wab, va, vab, Wc, Wcb,
            kp, h_hist, c_ws, ctx_ws, A_bf);
    gemm_out<<<dim3(250, 8), 256, 0, stream>>>(A_bf, Wh_bf, Whb, (float*)d_out);
}

// Round 4
// 1517.592 us; speedup vs baseline: 4.3241x; 4.3241x over previous
//
#include <hip/hip_runtime.h>
#include <stdint.h>

#define VOCAB 32000
#define EMBD  256
#define HID   512
#define SEQ   32
#define NB    32

using bf16x8 = __attribute__((ext_vector_type(8))) short;
using f32x4  = __attribute__((ext_vector_type(4))) float;

__device__ __forceinline__ unsigned short f2bf(float x){
    unsigned int u = __float_as_uint(x);
    u += 0x7fffu + ((u >> 16) & 1u);
    return (unsigned short)(u >> 16);
}
__device__ __forceinline__ float sigm(float x){ return 1.0f / (1.0f + expf(-x)); }

// ---------------- init: h0 = enc_last, c0 = 0 ----------------
__global__ __launch_bounds__(256) void init_kernel(
    const float* __restrict__ encl, float* __restrict__ h0, float* __restrict__ c0)
{
    int i = blockIdx.x * 256 + threadIdx.x;
    if (i < NB * HID) { h0[i] = encl[i]; c0[i] = 0.f; }
}

// ---------------- generic tall GEMM: out[R][J] = X[R][K] @ W[J][K]^T + b ----------------
// MODE 0: f32 out. MODE 1: tanh -> bf16 out with row perm (s*32+b -> b*32+s).
// MODE 2: X rows gathered from emb via tokens (teacher forcing).
// Block: 16 rows staged in LDS, 256 threads, 2 j-columns per thread (JPB=512).
template<int K, int MODE>
__global__ __launch_bounds__(256) void proj_gemm(
    const float* __restrict__ X, const float* __restrict__ W,
    const float* __restrict__ b1, const float* __restrict__ b2,
    void* __restrict__ outp, int Jtot,
    const int* __restrict__ tgt, const int* __restrict__ sosp)
{
    __shared__ float xs[16 * K];
    const int r0  = blockIdx.x * 16;
    const int tid = threadIdx.x;
    if constexpr (MODE == 2) {
        const int sos = sosp[0];
        for (int idx = tid; idx < 16 * (K / 4); idx += 256) {
            int r = idx / (K / 4), q = idx % (K / 4);
            int rg = r0 + r, t = rg >> 5, b = rg & 31;
            int tok = (t == 0) ? sos : tgt[b * SEQ + (t - 1)];
            *(float4*)&xs[r * K + q * 4] = *(const float4*)&X[tok * K + q * 4];
        }
    } else {
        for (int idx = tid; idx < 16 * (K / 4); idx += 256) {
            int r = idx / (K / 4), q = idx % (K / 4);
            *(float4*)&xs[r * K + q * 4] = *(const float4*)&X[(r0 + r) * K + q * 4];
        }
    }
    __syncthreads();

    const int j0 = blockIdx.y * 512 + tid;
    const int j1 = j0 + 256;
    const float* w0 = W + (long)j0 * K;
    const float* w1 = W + (long)j1 * K;
    float acc[16][2] = {};
    for (int k4 = 0; k4 < K / 4; ++k4) {
        float4 wa = *(const float4*)(w0 + k4 * 4);
        float4 wb = *(const float4*)(w1 + k4 * 4);
        #pragma unroll
        for (int r = 0; r < 16; ++r) {
            float4 x = *(const float4*)&xs[r * K + k4 * 4];
            acc[r][0] += wa.x * x.x + wa.y * x.y + wa.z * x.z + wa.w * x.w;
            acc[r][1] += wb.x * x.x + wb.y * x.y + wb.z * x.z + wb.w * x.w;
        }
    }
    float bv0 = b1[j0] + (b2 ? b2[j0] : 0.f);
    float bv1 = b1[j1] + (b2 ? b2[j1] : 0.f);
    #pragma unroll
    for (int r = 0; r < 16; ++r) {
        int rg = r0 + r;
        if constexpr (MODE == 1) {
            int orow = (rg & 31) * 32 + (rg >> 5);   // (s,b) -> b*32+s
            unsigned short* o = (unsigned short*)outp;
            o[orow * Jtot + j0] = f2bf(tanhf(acc[r][0] + bv0));
            o[orow * Jtot + j1] = f2bf(tanhf(acc[r][1] + bv1));
        } else {
            float* o = (float*)outp;
            o[rg * Jtot + j0] = acc[r][0] + bv0;
            o[rg * Jtot + j1] = acc[r][1] + bv1;
        }
    }
}

// ---------------- LSTM step (critical path): gates = gx[t] + h @ W_hh^T ----------------
// 256 blocks x 256 threads; block owns 2 h-outputs (8 gate rows); thread = (b, gate-row).
__global__ __launch_bounds__(256) void lstm_step(
    int t, const float* __restrict__ W_hh, const float* __restrict__ gx,
    float* __restrict__ h_hist, float* __restrict__ c_ws, float* __restrict__ cat)
{
    __shared__ float gtmp[256];
    const int tid  = threadIdx.x;
    const int b    = tid >> 3, slot = tid & 7;
    const int jb   = blockIdx.x * 2;
    const int g    = slot >> 1, jj = slot & 1;
    const int wrow = g * 512 + jb + jj;

    float acc = gx[(t * NB + b) * 2048 + wrow];
    const float4* wr = (const float4*)(W_hh + (long)wrow * HID);
    const float4* hr = (const float4*)(h_hist + t * (NB * HID) + b * HID);
    #pragma unroll 8
    for (int k4 = 0; k4 < HID / 4; ++k4) {
        float4 w = wr[k4], h4 = hr[k4];
        acc += w.x * h4.x + w.y * h4.y + w.z * h4.z + w.w * h4.w;
    }
    gtmp[tid] = acc;
    __syncthreads();
    if (slot < 2) {
        int j = jb + slot;
        int base = b * 8;
        float ig = sigm(gtmp[base + 0 + slot]);
        float fg = sigm(gtmp[base + 2 + slot]);
        float gg = tanhf(gtmp[base + 4 + slot]);
        float og = sigm(gtmp[base + 6 + slot]);
        float c  = c_ws[b * HID + j];
        float cn = fg * c + ig * gg;
        float hn = og * tanhf(cn);
        c_ws[b * HID + j] = cn;
        h_hist[(t + 1) * (NB * HID) + b * HID + j] = hn;
        cat[(t * NB + b) * 1024 + 512 + j] = hn;   // h-half of [ctx,h]
    }
}

// ---------------- attention for ALL (s,b) at once: 1024 blocks ----------------
__global__ __launch_bounds__(256) void attn_kernel(
    const float* __restrict__ q_all, const float* __restrict__ kp,
    const float* __restrict__ enc, const float* __restrict__ va,
    const float* __restrict__ vab, const int* __restrict__ mask,
    float* __restrict__ cat)
{
    __shared__ float qs[HID], vas[HID], ssm[32], es[32];
    const int r = blockIdx.x;            // s*32 + b
    const int b = r & 31;
    const int tid = threadIdx.x;
    for (int k = tid; k < HID; k += 256) { qs[k] = q_all[r * HID + k]; vas[k] = va[k]; }
    __syncthreads();
    const int l = tid >> 3, jt = tid & 7;
    float sp = 0.f;
    const float* kpl = kp + (b * SEQ + l) * HID;
    for (int jj = 0; jj < 64; ++jj) {
        int j = jt + jj * 8;
        sp += vas[j] * tanhf(qs[j] + kpl[j]);
    }
    sp += __shfl_xor(sp, 1); sp += __shfl_xor(sp, 2); sp += __shfl_xor(sp, 4);
    if (jt == 0) {
        float sc = sp + vab[0];
        if (mask[b * SEQ + l] == 0) sc = -1e10f;
        ssm[l] = sc;
    }
    __syncthreads();
    float m = -3.0e38f;
    #pragma unroll
    for (int i = 0; i < 32; ++i) m = fmaxf(m, ssm[i]);
    if (tid < 32) es[tid] = expf(ssm[tid] - m);
    __syncthreads();
    float sum = 0.f;
    #pragma unroll
    for (int i = 0; i < 32; ++i) sum += es[i];
    float rs = 1.0f / sum;
    #pragma unroll
    for (int jj = 0; jj < 2; ++jj) {
        int j = tid + jj * 256;
        float cacc = 0.f;
        const float* eb = enc + (b * SEQ) * HID + j;
        #pragma unroll 8
        for (int ll = 0; ll < 32; ++ll) cacc += es[ll] * eb[ll * HID];
        cat[r * 1024 + j] = cacc * rs;   // ctx-half of [ctx,h]
    }
}

// ---------------- final GEMM: out[1024][32000] = A_bf @ bf16(Wh)^T + bias ----------------
// M-tile 256, N-tile 128; Wh converted f32->bf16 during LDS staging (no prep pass).
__global__ __launch_bounds__(256) void gemm_out(
    const unsigned short* __restrict__ A, const float* __restrict__ Wf,
    const float* __restrict__ bias, float* __restrict__ out)
{
    __shared__ unsigned short At[256 * 32];
    __shared__ unsigned short Bt[128 * 32];
    const int N0 = blockIdx.x * 128;
    const int M0 = blockIdx.y * 256;
    const int tid  = threadIdx.x;
    const int lane = tid & 63, wv = tid >> 6;
    const int wm = wv >> 1, wn = wv & 1;

    f32x4 acc[8][4];
    #pragma unroll
    for (int i = 0; i < 8; ++i)
        #pragma unroll
        for (int j = 0; j < 4; ++j)
            acc[i][j] = (f32x4){0.f, 0.f, 0.f, 0.f};

    for (int kt = 0; kt < 16; ++kt) {
        const int k0 = kt * 32;
        __syncthreads();
        for (int c = tid; c < 1024; c += 256) {           // A: 256 rows x 32 bf16
            int row = c >> 2, q = c & 3;
            *(uint4*)&At[row * 32 + q * 8] = *(const uint4*)&A[(M0 + row) * 512 + k0 + q * 8];
        }
        for (int c = tid; c < 1024; c += 256) {           // B: 128 rows x 32 f32 -> bf16
            int row = c >> 3, q = c & 7;
            float4 v = *(const float4*)&Wf[(long)(N0 + row) * 512 + k0 + q * 4];
            ushort4 u;
            u.x = f2bf(v.x); u.y = f2bf(v.y); u.z = f2bf(v.z); u.w = f2bf(v.w);
            *(ushort4*)&Bt[row * 32 + q * 4] = u;
        }
        __syncthreads();
        const int koff = (lane >> 4) * 8;
        bf16x8 fa[8], fb[4];
        #pragma unroll
        for (int i = 0; i < 8; ++i)
            fa[i] = *(const bf16x8*)&At[(wm * 128 + i * 16 + (lane & 15)) * 32 + koff];
        #pragma unroll
        for (int j = 0; j < 4; ++j)
            fb[j] = *(const bf16x8*)&Bt[(wn * 64 + j * 16 + (lane & 15)) * 32 + koff];
        #pragma unroll
        for (int i = 0; i < 8; ++i)
            #pragma unroll
            for (int j = 0; j < 4; ++j)
                acc[i][j] = __builtin_amdgcn_mfma_f32_16x16x32_bf16(fa[i], fb[j], acc[i][j], 0, 0, 0);
    }
    const int rbase = (lane >> 4) * 4;
    const int cbase = lane & 15;
    #pragma unroll
    for (int i = 0; i < 8; ++i) {
        #pragma unroll
        for (int j = 0; j < 4; ++j) {
            int col = N0 + wn * 64 + j * 16 + cbase;
            float bv = bias[col];
            #pragma unroll
            for (int r = 0; r < 4; ++r) {
                int row = M0 + wm * 128 + i * 16 + rbase + r;
                out[(long)row * VOCAB + col] = acc[i][j][r] + bv;
            }
        }
    }
}

extern "C" void kernel_launch(void* const* d_in, const int* in_sizes, int n_in,
                              void* d_out, int out_size, void* d_ws, size_t ws_size,
                              hipStream_t stream)
{
    const int*   mask = (const int*)d_in[0];
    const float* enc  = (const float*)d_in[1];
    const float* encl = (const float*)d_in[2];
    const int*   tgt  = (const int*)d_in[3];
    const int*   sosp = (const int*)d_in[4];
    const float* emb  = (const float*)d_in[5];
    const float* W_ih = (const float*)d_in[6];
    const float* W_hh = (const float*)d_in[7];
    const float* b_ih = (const float*)d_in[8];
    const float* b_hh = (const float*)d_in[9];
    const float* Wa   = (const float*)d_in[10];
    const float* Wab  = (const float*)d_in[11];
    const float* Ua   = (const float*)d_in[12];
    const float* Uab  = (const float*)d_in[13];
    const float* va   = (const float*)d_in[14];
    const float* vab  = (const float*)d_in[15];
    const float* Wc   = (const float*)d_in[16];
    const float* Wcb  = (const float*)d_in[17];
    const float* Wh   = (const float*)d_in[18];
    const float* Whb  = (const float*)d_in[19];

    char* ws = (char*)d_ws;                              // total 20.1 MB
    float* h_hist = (float*)(ws);                        // [33][32][512]   2,162,688 B
    float* c_ws   = (float*)(ws + 2162688);              // [32][512]          65,536 B
    float* gx     = (float*)(ws + 2228224);              // [1024][2048]    8,388,608 B
    float* kp     = (float*)(ws + 10616832);             // [1024][512]     2,097,152 B
    float* q_all  = (float*)(ws + 12713984);             // [1024][512]     2,097,152 B
    float* cat    = (float*)(ws + 14811136);             // [1024][1024]    4,194,304 B
    unsigned short* A_bf = (unsigned short*)(ws + 19005440); // [1024][512] 1,048,576 B

    init_kernel<<<64, 256, 0, stream>>>(encl, h_hist, c_ws);
    // key_proj = enc @ Ua^T + Uab
    proj_gemm<512, 0><<<dim3(64, 1), 256, 0, stream>>>(enc, Ua, Uab, nullptr, kp, 512, nullptr, nullptr);
    // gx = emb[tokens] @ W_ih^T + (b_ih + b_hh)   (teacher-forced inputs, all steps)
    proj_gemm<256, 2><<<dim3(64, 4), 256, 0, stream>>>(emb, W_ih, b_ih, b_hh, gx, 2048, tgt, sosp);
    // sequential LSTM (the only true critical path)
    for (int t = 0; t < SEQ; ++t)
        lstm_step<<<256, 256, 0, stream>>>(t, W_hh, gx, h_hist, c_ws, cat);
    // q = h @ Wa^T + Wab for all steps at once
    proj_gemm<512, 0><<<dim3(64, 1), 256, 0, stream>>>(h_hist + NB * HID, Wa, Wab, nullptr, q_all, 512, nullptr, nullptr);
    // attention + ctx for all (s,b)
    attn_kernel<<<1024, 256, 0, stream>>>(q_all, kp, enc, va, vab, mask, cat);
    // a = tanh([ctx,h] @ Wc^T + Wcb) -> bf16, rows permuted to (b*32+s)
    proj_gemm<1024, 1><<<dim3(64, 1), 256, 0, stream>>>(cat, Wc, Wcb, nullptr, A_bf, 512, nullptr, nullptr);
    // out = A @ bf16(Wh)^T + Whb
    gemm_out<<<dim3(250, 4), 256, 0, stream>>>(A_bf, Wh, Whb, (float*)d_out);
}